// Round 18
// baseline (186.315 us; speedup 1.0000x reference)
//
#include <hip/hip_runtime.h>
#include <stdint.h>

#define TPB 256
#define SPAN 512        // nodes per dest bucket (bucket = col>>9)
#define LSH 9           // log2(SPAN)
#define PART_B 512      // partition blocks (two per CU: occupancy lever, R18)
#define PART_T 1024     // threads in hist/partition/sort kernels
#define SCAN_T 1024
#define SCAN_B 4096     // elements per scan block (1024 thr x 4)
#define SORT_CAP 35840  // words of dynamic LDS sort buffer (140KB); W ~32653±181

// ---------------------------------------------------------------------------
// GCN 3-layer forward on MI355X.
// R18 = R17 (184.6us) with PART_B 256->512. Evidence across R12/R16/R17:
// p_part dur is INSENSITIVE to write amp 1.1-1.6 (52/49/50us) -> it is
// scattered-store/atomic issue-rate bound at 1 block/CU (16/32 waves).
// PART_B=512 -> 2 blocks/CU (32 waves/CU). Run length halves to 256B (amp
// expected ~1.8-2) but R8->R9 already measured occupancy 2x beating amp
// 1.1->2.6 at scalar ILP (88->69us); here ILP-4 on top. Single-parameter
// A/B; all grids/windows parameterized by PART_B.
// Pipeline: p_hist | scan(in place) | p_part | p_sort | xw1d | 3x gather.
// agg[c] = dinv[c]*(sum dxw[r] + dxw[c]). WS ~56.4MB. R3 fallback kept.
// ---------------------------------------------------------------------------

// ---------------- bucket partition ----------------

__global__ __launch_bounds__(PART_T) void p_hist(
    const int* __restrict__ col, uint32_t* __restrict__ H,
    int NB, int E, int PBE) {
    __shared__ uint32_t cnt[1024];
    for (int i = threadIdx.x; i < NB; i += PART_T) cnt[i] = 0u;
    __syncthreads();
    int blk = blockIdx.x;
    int s = blk * PBE, e = min(E, s + PBE);
    for (int i = s + (threadIdx.x << 2); i < e; i += (PART_T << 2)) {
        if (i + 4 <= e && ((i & 3) == 0)) {
            int4 c4 = *(const int4*)(col + i);
            atomicAdd(&cnt[c4.x >> LSH], 1u);
            atomicAdd(&cnt[c4.y >> LSH], 1u);
            atomicAdd(&cnt[c4.z >> LSH], 1u);
            atomicAdd(&cnt[c4.w >> LSH], 1u);
        } else {
            for (int k = i; k < min(e, i + 4); ++k)
                atomicAdd(&cnt[col[k] >> LSH], 1u);
        }
    }
    __syncthreads();
    for (int i = threadIdx.x; i < NB; i += PART_T)
        H[(size_t)i * PART_B + blk] = cnt[i];
}

__global__ __launch_bounds__(SCAN_T) void k_scan1(
    const unsigned int* __restrict__ in, unsigned int* __restrict__ partial,
    unsigned int* __restrict__ bsum, int M) {
    __shared__ unsigned int sm[SCAN_T];
    int tid  = threadIdx.x;
    int base = blockIdx.x * SCAN_B + tid * 4;
    unsigned int v0 = (base + 0 < M) ? in[base + 0] : 0u;
    unsigned int v1 = (base + 1 < M) ? in[base + 1] : 0u;
    unsigned int v2 = (base + 2 < M) ? in[base + 2] : 0u;
    unsigned int v3 = (base + 3 < M) ? in[base + 3] : 0u;
    unsigned int s = v0 + v1 + v2 + v3;
    sm[tid] = s;
    __syncthreads();
    for (int off = 1; off < SCAN_T; off <<= 1) {
        unsigned int t = (tid >= off) ? sm[tid - off] : 0u;
        __syncthreads();
        sm[tid] += t;
        __syncthreads();
    }
    unsigned int excl = sm[tid] - s;
    if (base + 0 < M) partial[base + 0] = excl;
    if (base + 1 < M) partial[base + 1] = excl + v0;
    if (base + 2 < M) partial[base + 2] = excl + v0 + v1;
    if (base + 3 < M) partial[base + 3] = excl + v0 + v1 + v2;
    if (tid == SCAN_T - 1) bsum[blockIdx.x] = sm[SCAN_T - 1];
}

__global__ void k_scan2(unsigned int* __restrict__ bsum, int nb) {
    if (threadIdx.x == 0 && blockIdx.x == 0) {
        unsigned int run = 0;
        for (int i = 0; i < nb; ++i) {
            unsigned int t = bsum[i];
            bsum[i] = run;
            run += t;
        }
    }
}

__global__ __launch_bounds__(TPB) void k_scan3(
    const unsigned int* __restrict__ partial, const unsigned int* __restrict__ bsum,
    unsigned int* __restrict__ outp, int M, int E) {
    int i = blockIdx.x * TPB + threadIdx.x;
    if (i < M) outp[i] = partial[i] + bsum[i / SCAN_B];
    if (i == 0) outp[M] = (unsigned int)E;
}

// Partition: bpack[slot] = (row<<LSH)|ldest, bucket-grouped, ~256B runs.
// STRIDED 4x unroll (per-instruction wave pattern = 64 consecutive edges),
// 2 blocks/CU.
__global__ __launch_bounds__(PART_T) void p_part(
    const int* __restrict__ row, const int* __restrict__ col,
    const uint32_t* __restrict__ O, uint32_t* __restrict__ bpack,
    int NB, int E, int PBE) {
    __shared__ uint32_t cur[1024];
    int blk = blockIdx.x;
    for (int i = threadIdx.x; i < NB; i += PART_T)
        cur[i] = O[(size_t)i * PART_B + blk];
    __syncthreads();
    int s = blk * PBE, e = min(E, s + PBE);
    int i = s + threadIdx.x;
    for (; i + 3 * PART_T < e; i += 4 * PART_T) {
        int c0 = col[i];
        int c1 = col[i + PART_T];
        int c2 = col[i + 2 * PART_T];
        int c3 = col[i + 3 * PART_T];
        int r0 = row[i];
        int r1 = row[i + PART_T];
        int r2 = row[i + 2 * PART_T];
        int r3 = row[i + 3 * PART_T];
        uint32_t s0 = atomicAdd(&cur[c0 >> LSH], 1u);
        uint32_t s1 = atomicAdd(&cur[c1 >> LSH], 1u);
        uint32_t s2 = atomicAdd(&cur[c2 >> LSH], 1u);
        uint32_t s3 = atomicAdd(&cur[c3 >> LSH], 1u);
        bpack[s0] = ((uint32_t)r0 << LSH) | (uint32_t)(c0 & (SPAN - 1));
        bpack[s1] = ((uint32_t)r1 << LSH) | (uint32_t)(c1 & (SPAN - 1));
        bpack[s2] = ((uint32_t)r2 << LSH) | (uint32_t)(c2 & (SPAN - 1));
        bpack[s3] = ((uint32_t)r3 << LSH) | (uint32_t)(c3 & (SPAN - 1));
    }
    for (; i < e; i += PART_T) {
        int c = col[i];
        uint32_t slot = atomicAdd(&cur[c >> LSH], 1u);
        bpack[slot] = ((uint32_t)row[i] << LSH) | (uint32_t)(c & (SPAN - 1));
    }
}

// Per-bucket counting sort (512-node buckets): uint4 window reads, LDS
// staging (140KB dynamic), int4 coalesced csr writeout. Emits indptr+dinv.
extern __shared__ uint32_t sort_buf[];
__global__ __launch_bounds__(PART_T) void p_sort(
    const uint32_t* __restrict__ bpack, const uint32_t* __restrict__ O,
    int* __restrict__ csr_row, unsigned int* __restrict__ indptr,
    float* __restrict__ dinv, int NB, int N, int E) {
    __shared__ uint32_t hist[SPAN];
    __shared__ uint32_t cur[SPAN];
    int b = blockIdx.x;
    int t = threadIdx.x;
    if (t < SPAN) hist[t] = 0u;
    __syncthreads();
    uint32_t s = O[(size_t)b * PART_B];
    uint32_t e = O[(size_t)(b + 1) * PART_B];  // b+1==NB -> O[M]==E sentinel
    uint32_t W = e - s;
    uint32_t as = (s + 3u) & ~3u;  // first 16B-aligned index
    if ((uint32_t)t < as - s && s + t < e)
        atomicAdd(&hist[bpack[s + t] & (SPAN - 1)], 1u);
    for (uint32_t i = as + ((uint32_t)t << 2); i < e; i += (PART_T << 2)) {
        if (i + 4u <= e) {
            uint4 v4 = *(const uint4*)(bpack + i);
            atomicAdd(&hist[v4.x & (SPAN - 1)], 1u);
            atomicAdd(&hist[v4.y & (SPAN - 1)], 1u);
            atomicAdd(&hist[v4.z & (SPAN - 1)], 1u);
            atomicAdd(&hist[v4.w & (SPAN - 1)], 1u);
        } else {
            for (uint32_t k = i; k < e; ++k)
                atomicAdd(&hist[bpack[k] & (SPAN - 1)], 1u);
        }
    }
    __syncthreads();
    if (t < SPAN) cur[t] = hist[t];
    __syncthreads();
    for (int off = 1; off < SPAN; off <<= 1) {  // Hillis-Steele inclusive scan
        uint32_t v = (t < SPAN && t >= off) ? cur[t - off] : 0u;
        __syncthreads();
        if (t < SPAN) cur[t] += v;
        __syncthreads();
    }
    if (t < SPAN) {
        uint32_t excl = cur[t] - hist[t];
        int n = b * SPAN + t;
        if (n < N) {
            indptr[n] = s + excl;                      // dense: csr base == bpack base
            dinv[n]   = rsqrtf((float)(hist[t] + 1u)); // +1 = self loop
            if (n == N - 1) indptr[N] = (unsigned int)E;
        }
        cur[t] = excl;  // window-local cursor
    }
    __syncthreads();
    if (W <= SORT_CAP) {
        if ((uint32_t)t < as - s && s + t < e) {
            uint32_t v = bpack[s + t];
            uint32_t slot = atomicAdd(&cur[v & (SPAN - 1)], 1u);
            sort_buf[slot] = v >> LSH;
        }
        for (uint32_t i = as + ((uint32_t)t << 2); i < e; i += (PART_T << 2)) {
            if (i + 4u <= e) {
                uint4 v4 = *(const uint4*)(bpack + i);
                uint32_t s0 = atomicAdd(&cur[v4.x & (SPAN - 1)], 1u);
                uint32_t s1 = atomicAdd(&cur[v4.y & (SPAN - 1)], 1u);
                uint32_t s2 = atomicAdd(&cur[v4.z & (SPAN - 1)], 1u);
                uint32_t s3 = atomicAdd(&cur[v4.w & (SPAN - 1)], 1u);
                sort_buf[s0] = v4.x >> LSH;
                sort_buf[s1] = v4.y >> LSH;
                sort_buf[s2] = v4.z >> LSH;
                sort_buf[s3] = v4.w >> LSH;
            } else {
                for (uint32_t k = i; k < e; ++k) {
                    uint32_t v = bpack[k];
                    uint32_t slot = atomicAdd(&cur[v & (SPAN - 1)], 1u);
                    sort_buf[slot] = v >> LSH;
                }
            }
        }
        __syncthreads();
        uint32_t pro = as - s;  // elements before aligned base (0..3)
        if ((uint32_t)t < pro && (uint32_t)t < W) csr_row[s + t] = (int)sort_buf[t];
        for (uint32_t j = pro + ((uint32_t)t << 2); j < W; j += (PART_T << 2)) {
            if (j + 4u <= W) {
                *(int4*)(csr_row + s + j) =
                    make_int4((int)sort_buf[j], (int)sort_buf[j + 1],
                              (int)sort_buf[j + 2], (int)sort_buf[j + 3]);
            } else {
                for (uint32_t k = j; k < W; ++k) csr_row[s + k] = (int)sort_buf[k];
            }
        }
    } else {
        // statistical fallback (+17sigma): direct scattered stores
        for (uint32_t i = s + t; i < e; i += PART_T) {
            uint32_t v = bpack[i];
            uint32_t slot = atomicAdd(&cur[v & (SPAN - 1)], 1u);
            csr_row[s + slot] = (int)(v >> LSH);
        }
    }
}

// ---------------- node / gather kernels ----------------

// dxw1 = dinv * (x @ W1): 2 nodes per wave, float4 loads (1KB/wave),
// half-wave (32-lane) shuffle reduce.
__global__ __launch_bounds__(TPB) void k_xw1d(
    const float* __restrict__ x, const float* __restrict__ W1,
    const float* __restrict__ dinv, float* __restrict__ dxw1, int N) {
    __shared__ float sW[512];  // 128 x 4
    for (int t = threadIdx.x; t < 512; t += TPB) sW[t] = W1[t];
    __syncthreads();
    int gid  = blockIdx.x * TPB + threadIdx.x;
    int wave = gid >> 6;
    int lane = threadIdx.x & 63;
    int n    = wave * 2 + (lane >> 5);
    if (n >= N) return;
    float4 v = *(const float4*)(x + (size_t)wave * 256 + 4 * lane);
    const float* wb = &sW[(4 * (lane & 31)) * 4];
    float a[4];
#pragma unroll
    for (int j = 0; j < 4; ++j)
        a[j] = v.x * wb[0 * 4 + j] + v.y * wb[1 * 4 + j] +
               v.z * wb[2 * 4 + j] + v.w * wb[3 * 4 + j];
#pragma unroll
    for (int off = 16; off > 0; off >>= 1) {
#pragma unroll
        for (int j = 0; j < 4; ++j) a[j] += __shfl_xor(a[j], off);
    }
    if ((lane & 31) == 0) {
        float d = dinv[n];
        *(float4*)(dxw1 + (size_t)n * 4) =
            make_float4(d * a[0], d * a[1], d * a[2], d * a[3]);
    }
}

__global__ __launch_bounds__(TPB) void k_gather44(
    const unsigned int* __restrict__ indptr, const int* __restrict__ csr_row,
    const float* __restrict__ dinv, const float* __restrict__ dxw_in,
    const float* __restrict__ b, const float* __restrict__ W,
    float* __restrict__ dxw_out, int N) {
    int gid  = blockIdx.x * TPB + threadIdx.x;
    int node = gid >> 4;
    int sub  = gid & 15;
    if (node >= N) return;
    int e0 = (int)indptr[node], e1 = (int)indptr[node + 1];
    float4 acc = make_float4(0.f, 0.f, 0.f, 0.f);
    for (int j = e0 + sub; j < e1; j += 16) {
        int r = csr_row[j];
        float4 m = *(const float4*)(dxw_in + (size_t)r * 4);
        acc.x += m.x; acc.y += m.y; acc.z += m.z; acc.w += m.w;
    }
#pragma unroll
    for (int off = 1; off < 16; off <<= 1) {
        acc.x += __shfl_xor(acc.x, off);
        acc.y += __shfl_xor(acc.y, off);
        acc.z += __shfl_xor(acc.z, off);
        acc.w += __shfl_xor(acc.w, off);
    }
    if (sub == 0) {
        float d = dinv[node];
        float4 sv = *(const float4*)(dxw_in + (size_t)node * 4);
        float h0 = fmaxf(d * (acc.x + sv.x) + b[0], 0.f);
        float h1 = fmaxf(d * (acc.y + sv.y) + b[1], 0.f);
        float h2 = fmaxf(d * (acc.z + sv.z) + b[2], 0.f);
        float h3 = fmaxf(d * (acc.w + sv.w) + b[3], 0.f);
        float o[4];
#pragma unroll
        for (int j = 0; j < 4; ++j)
            o[j] = h0 * W[0 * 4 + j] + h1 * W[1 * 4 + j] +
                   h2 * W[2 * 4 + j] + h3 * W[3 * 4 + j];
        *(float4*)(dxw_out + (size_t)node * 4) =
            make_float4(d * o[0], d * o[1], d * o[2], d * o[3]);
    }
}

__global__ __launch_bounds__(TPB) void k_gather42(
    const unsigned int* __restrict__ indptr, const int* __restrict__ csr_row,
    const float* __restrict__ dinv, const float* __restrict__ dxw_in,
    const float* __restrict__ b, const float* __restrict__ W,
    float* __restrict__ dxw_out, int N) {
    int gid  = blockIdx.x * TPB + threadIdx.x;
    int node = gid >> 4;
    int sub  = gid & 15;
    if (node >= N) return;
    int e0 = (int)indptr[node], e1 = (int)indptr[node + 1];
    float4 acc = make_float4(0.f, 0.f, 0.f, 0.f);
    for (int j = e0 + sub; j < e1; j += 16) {
        int r = csr_row[j];
        float4 m = *(const float4*)(dxw_in + (size_t)r * 4);
        acc.x += m.x; acc.y += m.y; acc.z += m.z; acc.w += m.w;
    }
#pragma unroll
    for (int off = 1; off < 16; off <<= 1) {
        acc.x += __shfl_xor(acc.x, off);
        acc.y += __shfl_xor(acc.y, off);
        acc.z += __shfl_xor(acc.z, off);
        acc.w += __shfl_xor(acc.w, off);
    }
    if (sub == 0) {
        float d = dinv[node];
        float4 sv = *(const float4*)(dxw_in + (size_t)node * 4);
        float h0 = fmaxf(d * (acc.x + sv.x) + b[0], 0.f);
        float h1 = fmaxf(d * (acc.y + sv.y) + b[1], 0.f);
        float h2 = fmaxf(d * (acc.z + sv.z) + b[2], 0.f);
        float h3 = fmaxf(d * (acc.w + sv.w) + b[3], 0.f);
        float o0 = h0 * W[0] + h1 * W[2] + h2 * W[4] + h3 * W[6];
        float o1 = h0 * W[1] + h1 * W[3] + h2 * W[5] + h3 * W[7];
        *(float2*)(dxw_out + (size_t)node * 2) = make_float2(d * o0, d * o1);
    }
}

__global__ __launch_bounds__(TPB) void k_gather2out(
    const unsigned int* __restrict__ indptr, const int* __restrict__ csr_row,
    const float* __restrict__ dinv, const float* __restrict__ dxw3,
    const float* __restrict__ b3, const float* __restrict__ Wc,
    const float* __restrict__ bc,
    float* __restrict__ out, float* __restrict__ y3out, int N) {
    int gid  = blockIdx.x * TPB + threadIdx.x;
    int node = gid >> 4;
    int sub  = gid & 15;
    if (node >= N) return;
    int e0 = (int)indptr[node], e1 = (int)indptr[node + 1];
    float ax = 0.f, ay = 0.f;
    for (int j = e0 + sub; j < e1; j += 16) {
        int r = csr_row[j];
        float2 m = *(const float2*)(dxw3 + (size_t)r * 2);
        ax += m.x; ay += m.y;
    }
#pragma unroll
    for (int off = 1; off < 16; off <<= 1) {
        ax += __shfl_xor(ax, off);
        ay += __shfl_xor(ay, off);
    }
    if (sub == 0) {
        float d = dinv[node];
        float2 sv = *(const float2*)(dxw3 + (size_t)node * 2);
        float y0 = fmaxf(d * (ax + sv.x) + b3[0], 0.f);
        float y1 = fmaxf(d * (ay + sv.y) + b3[1], 0.f);
        float o[4];
#pragma unroll
        for (int j = 0; j < 4; ++j)
            o[j] = y0 * Wc[0 * 4 + j] + y1 * Wc[1 * 4 + j] + bc[j];
        *(float4*)(out + (size_t)node * 4) = make_float4(o[0], o[1], o[2], o[3]);
        *(float2*)(y3out + (size_t)node * 2) = make_float2(y0, y1);
    }
}

// ---------------- R3 fallback kernels (atomic push path) ----------------

__global__ __launch_bounds__(TPB) void k_zero_deg(unsigned int* __restrict__ deg, int N) {
    int i = blockIdx.x * TPB + threadIdx.x;
    if (i < N) deg[i] = 0u;
}

__global__ __launch_bounds__(TPB) void k_deg(
    const int* __restrict__ col, unsigned int* __restrict__ deg, int E) {
    int e = blockIdx.x * TPB + threadIdx.x;
    if (e >= E) return;
    atomicAdd(&deg[col[e]], 1u);
}

__global__ __launch_bounds__(TPB) void k_dinv(const unsigned int* __restrict__ deg,
                                              float* __restrict__ dinv, int N) {
    int i = blockIdx.x * TPB + threadIdx.x;
    if (i < N) dinv[i] = rsqrtf((float)(deg[i] + 1u));
}

__global__ __launch_bounds__(TPB) void k_xw1(
    const float* __restrict__ x, const float* __restrict__ W1,
    const float* __restrict__ dinv,
    float* __restrict__ xw, float* __restrict__ agg, int N) {
    __shared__ float sW[512];
    for (int t = threadIdx.x; t < 512; t += TPB) sW[t] = W1[t];
    __syncthreads();
    int gid  = blockIdx.x * TPB + threadIdx.x;
    int node = gid >> 6;
    int lane = threadIdx.x & 63;
    if (node >= N) return;
    float2 v = *(const float2*)(x + (size_t)node * 128 + 2 * lane);
    const float* w0 = &sW[(2 * lane) * 4];
    const float* w1 = &sW[(2 * lane + 1) * 4];
    float a[4];
#pragma unroll
    for (int j = 0; j < 4; ++j) a[j] = v.x * w0[j] + v.y * w1[j];
#pragma unroll
    for (int off = 32; off > 0; off >>= 1) {
#pragma unroll
        for (int j = 0; j < 4; ++j) a[j] += __shfl_down(a[j], off);
    }
    if (lane == 0) {
        float d  = dinv[node];
        float d2 = d * d;
        *(float4*)(xw  + (size_t)node * 4) = make_float4(a[0], a[1], a[2], a[3]);
        *(float4*)(agg + (size_t)node * 4) =
            make_float4(d2 * a[0], d2 * a[1], d2 * a[2], d2 * a[3]);
    }
}

__global__ __launch_bounds__(TPB) void k_prop4(
    const int* __restrict__ row, const int* __restrict__ col,
    const float* __restrict__ dinv,
    const float* __restrict__ xw, float* __restrict__ agg, int E) {
    int e = blockIdx.x * TPB + threadIdx.x;
    if (e >= E) return;
    int r = row[e];
    int c = col[e];
    float nv = dinv[r] * dinv[c];
    float4 m = *(const float4*)(xw + (size_t)r * 4);
    float* a = agg + (size_t)c * 4;
    atomicAdd(a + 0, nv * m.x);
    atomicAdd(a + 1, nv * m.y);
    atomicAdd(a + 2, nv * m.z);
    atomicAdd(a + 3, nv * m.w);
}

__global__ __launch_bounds__(TPB) void k_prop2(
    const int* __restrict__ row, const int* __restrict__ col,
    const float* __restrict__ dinv,
    const float* __restrict__ xw2, float* __restrict__ agg2, int E) {
    int e = blockIdx.x * TPB + threadIdx.x;
    if (e >= E) return;
    int r = row[e];
    int c = col[e];
    float nv = dinv[r] * dinv[c];
    float2 m = *(const float2*)(xw2 + (size_t)r * 2);
    float* a = agg2 + (size_t)c * 2;
    atomicAdd(a + 0, nv * m.x);
    atomicAdd(a + 1, nv * m.y);
}

__global__ __launch_bounds__(TPB) void k_node2(
    const float* __restrict__ b1, const float* __restrict__ W2,
    const float* __restrict__ dinv,
    float* __restrict__ xw, float* __restrict__ agg, int N) {
    int i = blockIdx.x * TPB + threadIdx.x;
    if (i >= N) return;
    float4 av = *(const float4*)(agg + (size_t)i * 4);
    float h0 = fmaxf(av.x + b1[0], 0.f);
    float h1 = fmaxf(av.y + b1[1], 0.f);
    float h2 = fmaxf(av.z + b1[2], 0.f);
    float h3 = fmaxf(av.w + b1[3], 0.f);
    float o[4];
#pragma unroll
    for (int j = 0; j < 4; ++j)
        o[j] = h0 * W2[0 * 4 + j] + h1 * W2[1 * 4 + j] +
               h2 * W2[2 * 4 + j] + h3 * W2[3 * 4 + j];
    float d  = dinv[i];
    float d2 = d * d;
    *(float4*)(xw  + (size_t)i * 4) = make_float4(o[0], o[1], o[2], o[3]);
    *(float4*)(agg + (size_t)i * 4) = make_float4(d2 * o[0], d2 * o[1], d2 * o[2], d2 * o[3]);
}

__global__ __launch_bounds__(TPB) void k_node3(
    const float* __restrict__ b2, const float* __restrict__ W3,
    const float* __restrict__ dinv,
    const float* __restrict__ agg,
    float* __restrict__ xw3, float* __restrict__ agg3, int N) {
    int i = blockIdx.x * TPB + threadIdx.x;
    if (i >= N) return;
    float4 av = *(const float4*)(agg + (size_t)i * 4);
    float h0 = fmaxf(av.x + b2[0], 0.f);
    float h1 = fmaxf(av.y + b2[1], 0.f);
    float h2 = fmaxf(av.z + b2[2], 0.f);
    float h3 = fmaxf(av.w + b2[3], 0.f);
    float o0 = h0 * W3[0] + h1 * W3[2] + h2 * W3[4] + h3 * W3[6];
    float o1 = h0 * W3[1] + h1 * W3[3] + h2 * W3[5] + h3 * W3[7];
    float d  = dinv[i];
    float d2 = d * d;
    *(float2*)(xw3  + (size_t)i * 2) = make_float2(o0, o1);
    *(float2*)(agg3 + (size_t)i * 2) = make_float2(d2 * o0, d2 * o1);
}

__global__ __launch_bounds__(TPB) void k_out(
    const float* __restrict__ b3, const float* __restrict__ Wc,
    const float* __restrict__ bc,
    const float* __restrict__ agg3,
    float* __restrict__ out, float* __restrict__ y3out, int N) {
    int i = blockIdx.x * TPB + threadIdx.x;
    if (i >= N) return;
    float2 av = *(const float2*)(agg3 + (size_t)i * 2);
    float y0 = fmaxf(av.x + b3[0], 0.f);
    float y1 = fmaxf(av.y + b3[1], 0.f);
    float o[4];
#pragma unroll
    for (int j = 0; j < 4; ++j)
        o[j] = y0 * Wc[0 * 4 + j] + y1 * Wc[1 * 4 + j] + bc[j];
    *(float4*)(out + (size_t)i * 4) = make_float4(o[0], o[1], o[2], o[3]);
    *(float2*)(y3out + (size_t)i * 2) = make_float2(y0, y1);
}

extern "C" void kernel_launch(void* const* d_in, const int* in_sizes, int n_in,
                              void* d_out, int out_size, void* d_ws, size_t ws_size,
                              hipStream_t stream) {
    const float* x  = (const float*)d_in[0];
    const int*   ei = (const int*)d_in[1];   // int32 (harness converts integer inputs)
    const float* W1 = (const float*)d_in[2];
    const float* b1 = (const float*)d_in[3];
    const float* W2 = (const float*)d_in[4];
    const float* b2 = (const float*)d_in[5];
    const float* W3 = (const float*)d_in[6];
    const float* b3 = (const float*)d_in[7];
    const float* Wc = (const float*)d_in[8];
    const float* bc = (const float*)d_in[9];

    const int N = in_sizes[0] / 128;
    const int E = in_sizes[1] / 2;

    const int* row = ei;
    const int* col = ei + (size_t)E;

    const int NB  = (N + SPAN - 1) / SPAN;        // dest buckets (196)
    const int M   = NB * PART_B;                  // flattened hist size (~100K)
    const int PBE = (E + PART_B - 1) / PART_B;    // edges per partition block

    float* out   = (float*)d_out;                  // [N,4]
    float* y3out = (float*)d_out + (size_t)N * 4;  // [N,2]

    const int nblkN  = (N + TPB - 1) / TPB;
    const int nblkE  = (E + TPB - 1) / TPB;
    const int nblkW  = (N * 64 + TPB - 1) / TPB;          // wave-per-node (fallback)
    const int nblkX  = (((N + 1) / 2) * 64 + TPB - 1) / TPB;  // 2 nodes/wave
    const int nblkG  = (N * 16 + TPB - 1) / TPB;          // 16 threads/node
    const int nblkM  = (M + 1 + TPB - 1) / TPB;
    const int nblkS  = (M + SCAN_B - 1) / SCAN_B;         // scan blocks (~25)

    // Carve (~56.4MB). H is scanned in place (becomes O).
    size_t off = 0;
    auto carve = [&](size_t bytes) -> void* {
        void* r = (void*)((char*)d_ws + off);
        off += (bytes + 255) & ~(size_t)255;
        return r;
    };
    float*        dinv    = (float*)carve((size_t)N * 4);
    float*        dxw1    = (float*)carve((size_t)N * 4 * 4);
    float*        dxw2    = (float*)carve((size_t)N * 4 * 4);
    float*        dxw3    = (float*)carve((size_t)N * 2 * 4);
    unsigned int* indptr  = (unsigned int*)carve(((size_t)N + 1) * 4);
    uint32_t*     bsum    = (uint32_t*)carve(260 * 4);
    uint32_t*     H       = (uint32_t*)carve(((size_t)M + 1) * 4);  // -> O in place
    uint32_t*     bpack   = (uint32_t*)carve((size_t)E * 4);
    int*          csr_row = (int*)carve((size_t)E * 4);
    bool use_bucket = (off <= ws_size) && (NB <= 1024) && (N < (1 << 23));

    if (use_bucket) {
        size_t sort_lds = (size_t)SORT_CAP * 4;  // 140KB dynamic (+4KB static)
        hipFuncSetAttribute((const void*)p_sort,
                            hipFuncAttributeMaxDynamicSharedMemorySize,
                            (int)sort_lds);
        p_hist<<<PART_B, PART_T, 0, stream>>>(col, H, NB, E, PBE);
        k_scan1<<<nblkS, SCAN_T, 0, stream>>>(H, H, bsum, M);         // in-place
        k_scan2<<<1, 32, 0, stream>>>(bsum, nblkS);
        k_scan3<<<nblkM, TPB, 0, stream>>>(H, bsum, H, M, E);         // in-place
        p_part<<<PART_B, PART_T, 0, stream>>>(row, col, H, bpack, NB, E, PBE);
        p_sort<<<NB, PART_T, sort_lds, stream>>>(bpack, H, csr_row, indptr,
                                                 dinv, NB, N, E);
        k_xw1d<<<nblkX, TPB, 0, stream>>>(x, W1, dinv, dxw1, N);
        k_gather44<<<nblkG, TPB, 0, stream>>>(indptr, csr_row, dinv, dxw1, b1, W2, dxw2, N);
        k_gather42<<<nblkG, TPB, 0, stream>>>(indptr, csr_row, dinv, dxw2, b2, W3, dxw3, N);
        k_gather2out<<<nblkG, TPB, 0, stream>>>(indptr, csr_row, dinv, dxw3, b3, Wc, bc,
                                                out, y3out, N);
    } else {
        // R3 verified atomic-push fallback: recarve from base (~6MB).
        size_t foff = 0;
        auto fcarve = [&](size_t bytes) -> void* {
            void* r = (void*)((char*)d_ws + foff);
            foff += (bytes + 255) & ~(size_t)255;
            return r;
        };
        unsigned int* deg   = (unsigned int*)fcarve((size_t)N * 4);
        float*        fdinv = (float*)fcarve((size_t)N * 4);
        float*        xw    = (float*)fcarve((size_t)N * 4 * 4);
        float*        agg   = (float*)fcarve((size_t)N * 4 * 4);
        float*        xw3   = (float*)fcarve((size_t)N * 2 * 4);
        float*        agg3  = (float*)fcarve((size_t)N * 2 * 4);
        k_zero_deg<<<nblkN, TPB, 0, stream>>>(deg, N);
        k_deg<<<nblkE, TPB, 0, stream>>>(col, deg, E);
        k_dinv<<<nblkN, TPB, 0, stream>>>(deg, fdinv, N);
        k_xw1<<<nblkW, TPB, 0, stream>>>(x, W1, fdinv, xw, agg, N);
        k_prop4<<<nblkE, TPB, 0, stream>>>(row, col, fdinv, xw, agg, E);
        k_node2<<<nblkN, TPB, 0, stream>>>(b1, W2, fdinv, xw, agg, N);
        k_prop4<<<nblkE, TPB, 0, stream>>>(row, col, fdinv, xw, agg, E);
        k_node3<<<nblkN, TPB, 0, stream>>>(b2, W3, fdinv, agg, xw3, agg3, N);
        k_prop2<<<nblkE, TPB, 0, stream>>>(row, col, fdinv, xw3, agg3, E);
        k_out<<<nblkN, TPB, 0, stream>>>(b3, Wc, bc, agg3, out, y3out, N);
    }
}

// Round 19
// 183.977 us; speedup vs baseline: 1.0127x; 1.0127x over previous
//
#include <hip/hip_runtime.h>
#include <stdint.h>

#define TPB 256
#define SPAN 512        // nodes per dest bucket (bucket = col>>9)
#define LSH 9           // log2(SPAN)
#define PART_B 256      // partition blocks (one per CU; R18 proved 512 is null)
#define PART_T 1024     // threads in hist/partition/sort kernels
#define SCAN_T 1024
#define SCAN_B 4096     // elements per scan block (1024 thr x 4)
#define SORT_CAP 35840  // words of dynamic LDS sort buffer (140KB); W ~32653±181
#define NREG 9          // uint4 register chunks per thread (36 words >= 35840/1024)

// ---------------------------------------------------------------------------
// GCN 3-layer forward on MI355X.
// R19 = R17 (184.6us best; R18 proved p_part is at a per-CU scattered-store
// issue-rate floor ~50us insensitive to occupancy/ILP/amp -> PART_B back to
// 256) + p_sort single-pass via REGISTER STAGING: window loaded once into
// <=9 uint4 regs/thread (static-indexed unroll - no scratch), hist from
// regs, scan, scatter from regs into LDS, coalesced int4 writeout. Saves
// the 25.6MB window re-read (p_sort FETCH ~38->~13MB).
// Pipeline: p_hist | scan(in place) | p_part | p_sort | xw1d | 3x gather.
// agg[c] = dinv[c]*(sum dxw[r] + dxw[c]). WS ~56.2MB. R3 fallback kept.
// ---------------------------------------------------------------------------

// ---------------- bucket partition ----------------

__global__ __launch_bounds__(PART_T) void p_hist(
    const int* __restrict__ col, uint32_t* __restrict__ H,
    int NB, int E, int PBE) {
    __shared__ uint32_t cnt[1024];
    for (int i = threadIdx.x; i < NB; i += PART_T) cnt[i] = 0u;
    __syncthreads();
    int blk = blockIdx.x;
    int s = blk * PBE, e = min(E, s + PBE);
    for (int i = s + (threadIdx.x << 2); i < e; i += (PART_T << 2)) {
        if (i + 4 <= e && ((i & 3) == 0)) {
            int4 c4 = *(const int4*)(col + i);
            atomicAdd(&cnt[c4.x >> LSH], 1u);
            atomicAdd(&cnt[c4.y >> LSH], 1u);
            atomicAdd(&cnt[c4.z >> LSH], 1u);
            atomicAdd(&cnt[c4.w >> LSH], 1u);
        } else {
            for (int k = i; k < min(e, i + 4); ++k)
                atomicAdd(&cnt[col[k] >> LSH], 1u);
        }
    }
    __syncthreads();
    for (int i = threadIdx.x; i < NB; i += PART_T)
        H[(size_t)i * PART_B + blk] = cnt[i];
}

__global__ __launch_bounds__(SCAN_T) void k_scan1(
    const unsigned int* __restrict__ in, unsigned int* __restrict__ partial,
    unsigned int* __restrict__ bsum, int M) {
    __shared__ unsigned int sm[SCAN_T];
    int tid  = threadIdx.x;
    int base = blockIdx.x * SCAN_B + tid * 4;
    unsigned int v0 = (base + 0 < M) ? in[base + 0] : 0u;
    unsigned int v1 = (base + 1 < M) ? in[base + 1] : 0u;
    unsigned int v2 = (base + 2 < M) ? in[base + 2] : 0u;
    unsigned int v3 = (base + 3 < M) ? in[base + 3] : 0u;
    unsigned int s = v0 + v1 + v2 + v3;
    sm[tid] = s;
    __syncthreads();
    for (int off = 1; off < SCAN_T; off <<= 1) {
        unsigned int t = (tid >= off) ? sm[tid - off] : 0u;
        __syncthreads();
        sm[tid] += t;
        __syncthreads();
    }
    unsigned int excl = sm[tid] - s;
    if (base + 0 < M) partial[base + 0] = excl;
    if (base + 1 < M) partial[base + 1] = excl + v0;
    if (base + 2 < M) partial[base + 2] = excl + v0 + v1;
    if (base + 3 < M) partial[base + 3] = excl + v0 + v1 + v2;
    if (tid == SCAN_T - 1) bsum[blockIdx.x] = sm[SCAN_T - 1];
}

__global__ void k_scan2(unsigned int* __restrict__ bsum, int nb) {
    if (threadIdx.x == 0 && blockIdx.x == 0) {
        unsigned int run = 0;
        for (int i = 0; i < nb; ++i) {
            unsigned int t = bsum[i];
            bsum[i] = run;
            run += t;
        }
    }
}

__global__ __launch_bounds__(TPB) void k_scan3(
    const unsigned int* __restrict__ partial, const unsigned int* __restrict__ bsum,
    unsigned int* __restrict__ outp, int M, int E) {
    int i = blockIdx.x * TPB + threadIdx.x;
    if (i < M) outp[i] = partial[i] + bsum[i / SCAN_B];
    if (i == 0) outp[M] = (unsigned int)E;
}

// Partition: bpack[slot] = (row<<LSH)|ldest, bucket-grouped, 512B runs.
// STRIDED 4x unroll (per-instruction wave pattern = 64 consecutive edges).
__global__ __launch_bounds__(PART_T) void p_part(
    const int* __restrict__ row, const int* __restrict__ col,
    const uint32_t* __restrict__ O, uint32_t* __restrict__ bpack,
    int NB, int E, int PBE) {
    __shared__ uint32_t cur[1024];
    int blk = blockIdx.x;
    for (int i = threadIdx.x; i < NB; i += PART_T)
        cur[i] = O[(size_t)i * PART_B + blk];
    __syncthreads();
    int s = blk * PBE, e = min(E, s + PBE);
    int i = s + threadIdx.x;
    for (; i + 3 * PART_T < e; i += 4 * PART_T) {
        int c0 = col[i];
        int c1 = col[i + PART_T];
        int c2 = col[i + 2 * PART_T];
        int c3 = col[i + 3 * PART_T];
        int r0 = row[i];
        int r1 = row[i + PART_T];
        int r2 = row[i + 2 * PART_T];
        int r3 = row[i + 3 * PART_T];
        uint32_t s0 = atomicAdd(&cur[c0 >> LSH], 1u);
        uint32_t s1 = atomicAdd(&cur[c1 >> LSH], 1u);
        uint32_t s2 = atomicAdd(&cur[c2 >> LSH], 1u);
        uint32_t s3 = atomicAdd(&cur[c3 >> LSH], 1u);
        bpack[s0] = ((uint32_t)r0 << LSH) | (uint32_t)(c0 & (SPAN - 1));
        bpack[s1] = ((uint32_t)r1 << LSH) | (uint32_t)(c1 & (SPAN - 1));
        bpack[s2] = ((uint32_t)r2 << LSH) | (uint32_t)(c2 & (SPAN - 1));
        bpack[s3] = ((uint32_t)r3 << LSH) | (uint32_t)(c3 & (SPAN - 1));
    }
    for (; i < e; i += PART_T) {
        int c = col[i];
        uint32_t slot = atomicAdd(&cur[c >> LSH], 1u);
        bpack[slot] = ((uint32_t)row[i] << LSH) | (uint32_t)(c & (SPAN - 1));
    }
}

// Per-bucket counting sort (512-node buckets), SINGLE global read:
// window register-staged (<=9 uint4/thread, static-indexed), hist from
// regs, scan, scatter from regs into LDS, int4 coalesced csr writeout.
// Emits indptr + dinv. W>SORT_CAP statistical fallback = old 2-pass path.
extern __shared__ uint32_t sort_buf[];
__global__ __launch_bounds__(PART_T) void p_sort(
    const uint32_t* __restrict__ bpack, const uint32_t* __restrict__ O,
    int* __restrict__ csr_row, unsigned int* __restrict__ indptr,
    float* __restrict__ dinv, int NB, int N, int E) {
    __shared__ uint32_t hist[SPAN];
    __shared__ uint32_t cur[SPAN];
    int b = blockIdx.x;
    int t = threadIdx.x;
    if (t < SPAN) hist[t] = 0u;
    __syncthreads();
    uint32_t s = O[(size_t)b * PART_B];
    uint32_t e = O[(size_t)(b + 1) * PART_B];  // b+1==NB -> O[M]==E sentinel
    uint32_t W = e - s;
    uint32_t as = (s + 3u) & ~3u;              // first 16B-aligned index
    uint32_t nw4 = (e > as) ? ((e - as) >> 2) : 0u;  // full uint4 chunks
    uint32_t tail = (e > as) ? (e - as - nw4 * 4u) : 0u;
    bool fits = (W <= (uint32_t)SORT_CAP);

    uint4 regs[NREG];
    if (fits) {
        // single global read: stage window into registers (static indexing)
#pragma unroll
        for (int k = 0; k < NREG; ++k) {
            uint32_t ck = (uint32_t)t + (uint32_t)k * PART_T;
            if (ck < nw4) regs[k] = *(const uint4*)(bpack + as + (size_t)ck * 4u);
        }
        // prologue [s, as) + tail (scalar, <=3 elems each, from global)
        if ((uint32_t)t < as - s && s + t < e)
            atomicAdd(&hist[bpack[s + t] & (SPAN - 1)], 1u);
        if ((uint32_t)t < tail)
            atomicAdd(&hist[bpack[as + nw4 * 4u + t] & (SPAN - 1)], 1u);
        // hist from registers
#pragma unroll
        for (int k = 0; k < NREG; ++k) {
            uint32_t ck = (uint32_t)t + (uint32_t)k * PART_T;
            if (ck < nw4) {
                atomicAdd(&hist[regs[k].x & (SPAN - 1)], 1u);
                atomicAdd(&hist[regs[k].y & (SPAN - 1)], 1u);
                atomicAdd(&hist[regs[k].z & (SPAN - 1)], 1u);
                atomicAdd(&hist[regs[k].w & (SPAN - 1)], 1u);
            }
        }
    } else {
        // fallback hist pass (reads global)
        for (uint32_t i = s + t; i < e; i += PART_T)
            atomicAdd(&hist[bpack[i] & (SPAN - 1)], 1u);
    }
    __syncthreads();
    if (t < SPAN) cur[t] = hist[t];
    __syncthreads();
    for (int off = 1; off < SPAN; off <<= 1) {  // Hillis-Steele inclusive scan
        uint32_t v = (t < SPAN && t >= off) ? cur[t - off] : 0u;
        __syncthreads();
        if (t < SPAN) cur[t] += v;
        __syncthreads();
    }
    if (t < SPAN) {
        uint32_t excl = cur[t] - hist[t];
        int n = b * SPAN + t;
        if (n < N) {
            indptr[n] = s + excl;                      // dense: csr base == bpack base
            dinv[n]   = rsqrtf((float)(hist[t] + 1u)); // +1 = self loop
            if (n == N - 1) indptr[N] = (unsigned int)E;
        }
        cur[t] = excl;  // window-local cursor
    }
    __syncthreads();
    if (fits) {
        // scatter from registers into LDS
        if ((uint32_t)t < as - s && s + t < e) {
            uint32_t v = bpack[s + t];
            uint32_t slot = atomicAdd(&cur[v & (SPAN - 1)], 1u);
            sort_buf[slot] = v >> LSH;
        }
        if ((uint32_t)t < tail) {
            uint32_t v = bpack[as + nw4 * 4u + t];
            uint32_t slot = atomicAdd(&cur[v & (SPAN - 1)], 1u);
            sort_buf[slot] = v >> LSH;
        }
#pragma unroll
        for (int k = 0; k < NREG; ++k) {
            uint32_t ck = (uint32_t)t + (uint32_t)k * PART_T;
            if (ck < nw4) {
                uint32_t s0 = atomicAdd(&cur[regs[k].x & (SPAN - 1)], 1u);
                uint32_t s1 = atomicAdd(&cur[regs[k].y & (SPAN - 1)], 1u);
                uint32_t s2 = atomicAdd(&cur[regs[k].z & (SPAN - 1)], 1u);
                uint32_t s3 = atomicAdd(&cur[regs[k].w & (SPAN - 1)], 1u);
                sort_buf[s0] = regs[k].x >> LSH;
                sort_buf[s1] = regs[k].y >> LSH;
                sort_buf[s2] = regs[k].z >> LSH;
                sort_buf[s3] = regs[k].w >> LSH;
            }
        }
        __syncthreads();
        // coalesced writeout: scalar prologue to alignment, then int4
        uint32_t pro = as - s;  // elements before aligned base (0..3)
        if ((uint32_t)t < pro && (uint32_t)t < W) csr_row[s + t] = (int)sort_buf[t];
        for (uint32_t j = pro + ((uint32_t)t << 2); j < W; j += (PART_T << 2)) {
            if (j + 4u <= W) {
                *(int4*)(csr_row + s + j) =
                    make_int4((int)sort_buf[j], (int)sort_buf[j + 1],
                              (int)sort_buf[j + 2], (int)sort_buf[j + 3]);
            } else {
                for (uint32_t k = j; k < W; ++k) csr_row[s + k] = (int)sort_buf[k];
            }
        }
    } else {
        // statistical fallback (+17sigma): direct scattered stores
        for (uint32_t i = s + t; i < e; i += PART_T) {
            uint32_t v = bpack[i];
            uint32_t slot = atomicAdd(&cur[v & (SPAN - 1)], 1u);
            csr_row[s + slot] = (int)(v >> LSH);
        }
    }
}

// ---------------- node / gather kernels ----------------

// dxw1 = dinv * (x @ W1): 2 nodes per wave, float4 loads (1KB/wave),
// half-wave (32-lane) shuffle reduce.
__global__ __launch_bounds__(TPB) void k_xw1d(
    const float* __restrict__ x, const float* __restrict__ W1,
    const float* __restrict__ dinv, float* __restrict__ dxw1, int N) {
    __shared__ float sW[512];  // 128 x 4
    for (int t = threadIdx.x; t < 512; t += TPB) sW[t] = W1[t];
    __syncthreads();
    int gid  = blockIdx.x * TPB + threadIdx.x;
    int wave = gid >> 6;
    int lane = threadIdx.x & 63;
    int n    = wave * 2 + (lane >> 5);
    if (n >= N) return;
    float4 v = *(const float4*)(x + (size_t)wave * 256 + 4 * lane);
    const float* wb = &sW[(4 * (lane & 31)) * 4];
    float a[4];
#pragma unroll
    for (int j = 0; j < 4; ++j)
        a[j] = v.x * wb[0 * 4 + j] + v.y * wb[1 * 4 + j] +
               v.z * wb[2 * 4 + j] + v.w * wb[3 * 4 + j];
#pragma unroll
    for (int off = 16; off > 0; off >>= 1) {
#pragma unroll
        for (int j = 0; j < 4; ++j) a[j] += __shfl_xor(a[j], off);
    }
    if ((lane & 31) == 0) {
        float d = dinv[n];
        *(float4*)(dxw1 + (size_t)n * 4) =
            make_float4(d * a[0], d * a[1], d * a[2], d * a[3]);
    }
}

__global__ __launch_bounds__(TPB) void k_gather44(
    const unsigned int* __restrict__ indptr, const int* __restrict__ csr_row,
    const float* __restrict__ dinv, const float* __restrict__ dxw_in,
    const float* __restrict__ b, const float* __restrict__ W,
    float* __restrict__ dxw_out, int N) {
    int gid  = blockIdx.x * TPB + threadIdx.x;
    int node = gid >> 4;
    int sub  = gid & 15;
    if (node >= N) return;
    int e0 = (int)indptr[node], e1 = (int)indptr[node + 1];
    float4 acc = make_float4(0.f, 0.f, 0.f, 0.f);
    for (int j = e0 + sub; j < e1; j += 16) {
        int r = csr_row[j];
        float4 m = *(const float4*)(dxw_in + (size_t)r * 4);
        acc.x += m.x; acc.y += m.y; acc.z += m.z; acc.w += m.w;
    }
#pragma unroll
    for (int off = 1; off < 16; off <<= 1) {
        acc.x += __shfl_xor(acc.x, off);
        acc.y += __shfl_xor(acc.y, off);
        acc.z += __shfl_xor(acc.z, off);
        acc.w += __shfl_xor(acc.w, off);
    }
    if (sub == 0) {
        float d = dinv[node];
        float4 sv = *(const float4*)(dxw_in + (size_t)node * 4);
        float h0 = fmaxf(d * (acc.x + sv.x) + b[0], 0.f);
        float h1 = fmaxf(d * (acc.y + sv.y) + b[1], 0.f);
        float h2 = fmaxf(d * (acc.z + sv.z) + b[2], 0.f);
        float h3 = fmaxf(d * (acc.w + sv.w) + b[3], 0.f);
        float o[4];
#pragma unroll
        for (int j = 0; j < 4; ++j)
            o[j] = h0 * W[0 * 4 + j] + h1 * W[1 * 4 + j] +
                   h2 * W[2 * 4 + j] + h3 * W[3 * 4 + j];
        *(float4*)(dxw_out + (size_t)node * 4) =
            make_float4(d * o[0], d * o[1], d * o[2], d * o[3]);
    }
}

__global__ __launch_bounds__(TPB) void k_gather42(
    const unsigned int* __restrict__ indptr, const int* __restrict__ csr_row,
    const float* __restrict__ dinv, const float* __restrict__ dxw_in,
    const float* __restrict__ b, const float* __restrict__ W,
    float* __restrict__ dxw_out, int N) {
    int gid  = blockIdx.x * TPB + threadIdx.x;
    int node = gid >> 4;
    int sub  = gid & 15;
    if (node >= N) return;
    int e0 = (int)indptr[node], e1 = (int)indptr[node + 1];
    float4 acc = make_float4(0.f, 0.f, 0.f, 0.f);
    for (int j = e0 + sub; j < e1; j += 16) {
        int r = csr_row[j];
        float4 m = *(const float4*)(dxw_in + (size_t)r * 4);
        acc.x += m.x; acc.y += m.y; acc.z += m.z; acc.w += m.w;
    }
#pragma unroll
    for (int off = 1; off < 16; off <<= 1) {
        acc.x += __shfl_xor(acc.x, off);
        acc.y += __shfl_xor(acc.y, off);
        acc.z += __shfl_xor(acc.z, off);
        acc.w += __shfl_xor(acc.w, off);
    }
    if (sub == 0) {
        float d = dinv[node];
        float4 sv = *(const float4*)(dxw_in + (size_t)node * 4);
        float h0 = fmaxf(d * (acc.x + sv.x) + b[0], 0.f);
        float h1 = fmaxf(d * (acc.y + sv.y) + b[1], 0.f);
        float h2 = fmaxf(d * (acc.z + sv.z) + b[2], 0.f);
        float h3 = fmaxf(d * (acc.w + sv.w) + b[3], 0.f);
        float o0 = h0 * W[0] + h1 * W[2] + h2 * W[4] + h3 * W[6];
        float o1 = h0 * W[1] + h1 * W[3] + h2 * W[5] + h3 * W[7];
        *(float2*)(dxw_out + (size_t)node * 2) = make_float2(d * o0, d * o1);
    }
}

__global__ __launch_bounds__(TPB) void k_gather2out(
    const unsigned int* __restrict__ indptr, const int* __restrict__ csr_row,
    const float* __restrict__ dinv, const float* __restrict__ dxw3,
    const float* __restrict__ b3, const float* __restrict__ Wc,
    const float* __restrict__ bc,
    float* __restrict__ out, float* __restrict__ y3out, int N) {
    int gid  = blockIdx.x * TPB + threadIdx.x;
    int node = gid >> 4;
    int sub  = gid & 15;
    if (node >= N) return;
    int e0 = (int)indptr[node], e1 = (int)indptr[node + 1];
    float ax = 0.f, ay = 0.f;
    for (int j = e0 + sub; j < e1; j += 16) {
        int r = csr_row[j];
        float2 m = *(const float2*)(dxw3 + (size_t)r * 2);
        ax += m.x; ay += m.y;
    }
#pragma unroll
    for (int off = 1; off < 16; off <<= 1) {
        ax += __shfl_xor(ax, off);
        ay += __shfl_xor(ay, off);
    }
    if (sub == 0) {
        float d = dinv[node];
        float2 sv = *(const float2*)(dxw3 + (size_t)node * 2);
        float y0 = fmaxf(d * (ax + sv.x) + b3[0], 0.f);
        float y1 = fmaxf(d * (ay + sv.y) + b3[1], 0.f);
        float o[4];
#pragma unroll
        for (int j = 0; j < 4; ++j)
            o[j] = y0 * Wc[0 * 4 + j] + y1 * Wc[1 * 4 + j] + bc[j];
        *(float4*)(out + (size_t)node * 4) = make_float4(o[0], o[1], o[2], o[3]);
        *(float2*)(y3out + (size_t)node * 2) = make_float2(y0, y1);
    }
}

// ---------------- R3 fallback kernels (atomic push path) ----------------

__global__ __launch_bounds__(TPB) void k_zero_deg(unsigned int* __restrict__ deg, int N) {
    int i = blockIdx.x * TPB + threadIdx.x;
    if (i < N) deg[i] = 0u;
}

__global__ __launch_bounds__(TPB) void k_deg(
    const int* __restrict__ col, unsigned int* __restrict__ deg, int E) {
    int e = blockIdx.x * TPB + threadIdx.x;
    if (e >= E) return;
    atomicAdd(&deg[col[e]], 1u);
}

__global__ __launch_bounds__(TPB) void k_dinv(const unsigned int* __restrict__ deg,
                                              float* __restrict__ dinv, int N) {
    int i = blockIdx.x * TPB + threadIdx.x;
    if (i < N) dinv[i] = rsqrtf((float)(deg[i] + 1u));
}

__global__ __launch_bounds__(TPB) void k_xw1(
    const float* __restrict__ x, const float* __restrict__ W1,
    const float* __restrict__ dinv,
    float* __restrict__ xw, float* __restrict__ agg, int N) {
    __shared__ float sW[512];
    for (int t = threadIdx.x; t < 512; t += TPB) sW[t] = W1[t];
    __syncthreads();
    int gid  = blockIdx.x * TPB + threadIdx.x;
    int node = gid >> 6;
    int lane = threadIdx.x & 63;
    if (node >= N) return;
    float2 v = *(const float2*)(x + (size_t)node * 128 + 2 * lane);
    const float* w0 = &sW[(2 * lane) * 4];
    const float* w1 = &sW[(2 * lane + 1) * 4];
    float a[4];
#pragma unroll
    for (int j = 0; j < 4; ++j) a[j] = v.x * w0[j] + v.y * w1[j];
#pragma unroll
    for (int off = 32; off > 0; off >>= 1) {
#pragma unroll
        for (int j = 0; j < 4; ++j) a[j] += __shfl_down(a[j], off);
    }
    if (lane == 0) {
        float d  = dinv[node];
        float d2 = d * d;
        *(float4*)(xw  + (size_t)node * 4) = make_float4(a[0], a[1], a[2], a[3]);
        *(float4*)(agg + (size_t)node * 4) =
            make_float4(d2 * a[0], d2 * a[1], d2 * a[2], d2 * a[3]);
    }
}

__global__ __launch_bounds__(TPB) void k_prop4(
    const int* __restrict__ row, const int* __restrict__ col,
    const float* __restrict__ dinv,
    const float* __restrict__ xw, float* __restrict__ agg, int E) {
    int e = blockIdx.x * TPB + threadIdx.x;
    if (e >= E) return;
    int r = row[e];
    int c = col[e];
    float nv = dinv[r] * dinv[c];
    float4 m = *(const float4*)(xw + (size_t)r * 4);
    float* a = agg + (size_t)c * 4;
    atomicAdd(a + 0, nv * m.x);
    atomicAdd(a + 1, nv * m.y);
    atomicAdd(a + 2, nv * m.z);
    atomicAdd(a + 3, nv * m.w);
}

__global__ __launch_bounds__(TPB) void k_prop2(
    const int* __restrict__ row, const int* __restrict__ col,
    const float* __restrict__ dinv,
    const float* __restrict__ xw2, float* __restrict__ agg2, int E) {
    int e = blockIdx.x * TPB + threadIdx.x;
    if (e >= E) return;
    int r = row[e];
    int c = col[e];
    float nv = dinv[r] * dinv[c];
    float2 m = *(const float2*)(xw2 + (size_t)r * 2);
    float* a = agg2 + (size_t)c * 2;
    atomicAdd(a + 0, nv * m.x);
    atomicAdd(a + 1, nv * m.y);
}

__global__ __launch_bounds__(TPB) void k_node2(
    const float* __restrict__ b1, const float* __restrict__ W2,
    const float* __restrict__ dinv,
    float* __restrict__ xw, float* __restrict__ agg, int N) {
    int i = blockIdx.x * TPB + threadIdx.x;
    if (i >= N) return;
    float4 av = *(const float4*)(agg + (size_t)i * 4);
    float h0 = fmaxf(av.x + b1[0], 0.f);
    float h1 = fmaxf(av.y + b1[1], 0.f);
    float h2 = fmaxf(av.z + b1[2], 0.f);
    float h3 = fmaxf(av.w + b1[3], 0.f);
    float o[4];
#pragma unroll
    for (int j = 0; j < 4; ++j)
        o[j] = h0 * W2[0 * 4 + j] + h1 * W2[1 * 4 + j] +
               h2 * W2[2 * 4 + j] + h3 * W2[3 * 4 + j];
    float d  = dinv[i];
    float d2 = d * d;
    *(float4*)(xw  + (size_t)i * 4) = make_float4(o[0], o[1], o[2], o[3]);
    *(float4*)(agg + (size_t)i * 4) = make_float4(d2 * o[0], d2 * o[1], d2 * o[2], d2 * o[3]);
}

__global__ __launch_bounds__(TPB) void k_node3(
    const float* __restrict__ b2, const float* __restrict__ W3,
    const float* __restrict__ dinv,
    const float* __restrict__ agg,
    float* __restrict__ xw3, float* __restrict__ agg3, int N) {
    int i = blockIdx.x * TPB + threadIdx.x;
    if (i >= N) return;
    float4 av = *(const float4*)(agg + (size_t)i * 4);
    float h0 = fmaxf(av.x + b2[0], 0.f);
    float h1 = fmaxf(av.y + b2[1], 0.f);
    float h2 = fmaxf(av.z + b2[2], 0.f);
    float h3 = fmaxf(av.w + b2[3], 0.f);
    float o0 = h0 * W3[0] + h1 * W3[2] + h2 * W3[4] + h3 * W3[6];
    float o1 = h0 * W3[1] + h1 * W3[3] + h2 * W3[5] + h3 * W3[7];
    float d  = dinv[i];
    float d2 = d * d;
    *(float2*)(xw3  + (size_t)i * 2) = make_float2(o0, o1);
    *(float2*)(agg3 + (size_t)i * 2) = make_float2(d2 * o0, d2 * o1);
}

__global__ __launch_bounds__(TPB) void k_out(
    const float* __restrict__ b3, const float* __restrict__ Wc,
    const float* __restrict__ bc,
    const float* __restrict__ agg3,
    float* __restrict__ out, float* __restrict__ y3out, int N) {
    int i = blockIdx.x * TPB + threadIdx.x;
    if (i >= N) return;
    float2 av = *(const float2*)(agg3 + (size_t)i * 2);
    float y0 = fmaxf(av.x + b3[0], 0.f);
    float y1 = fmaxf(av.y + b3[1], 0.f);
    float o[4];
#pragma unroll
    for (int j = 0; j < 4; ++j)
        o[j] = y0 * Wc[0 * 4 + j] + y1 * Wc[1 * 4 + j] + bc[j];
    *(float4*)(out + (size_t)i * 4) = make_float4(o[0], o[1], o[2], o[3]);
    *(float2*)(y3out + (size_t)i * 2) = make_float2(y0, y1);
}

extern "C" void kernel_launch(void* const* d_in, const int* in_sizes, int n_in,
                              void* d_out, int out_size, void* d_ws, size_t ws_size,
                              hipStream_t stream) {
    const float* x  = (const float*)d_in[0];
    const int*   ei = (const int*)d_in[1];   // int32 (harness converts integer inputs)
    const float* W1 = (const float*)d_in[2];
    const float* b1 = (const float*)d_in[3];
    const float* W2 = (const float*)d_in[4];
    const float* b2 = (const float*)d_in[5];
    const float* W3 = (const float*)d_in[6];
    const float* b3 = (const float*)d_in[7];
    const float* Wc = (const float*)d_in[8];
    const float* bc = (const float*)d_in[9];

    const int N = in_sizes[0] / 128;
    const int E = in_sizes[1] / 2;

    const int* row = ei;
    const int* col = ei + (size_t)E;

    const int NB  = (N + SPAN - 1) / SPAN;        // dest buckets (196)
    const int M   = NB * PART_B;                  // flattened hist size (~50K)
    const int PBE = (E + PART_B - 1) / PART_B;    // edges per partition block

    float* out   = (float*)d_out;                  // [N,4]
    float* y3out = (float*)d_out + (size_t)N * 4;  // [N,2]

    const int nblkN  = (N + TPB - 1) / TPB;
    const int nblkE  = (E + TPB - 1) / TPB;
    const int nblkW  = (N * 64 + TPB - 1) / TPB;          // wave-per-node (fallback)
    const int nblkX  = (((N + 1) / 2) * 64 + TPB - 1) / TPB;  // 2 nodes/wave
    const int nblkG  = (N * 16 + TPB - 1) / TPB;          // 16 threads/node
    const int nblkM  = (M + 1 + TPB - 1) / TPB;
    const int nblkS  = (M + SCAN_B - 1) / SCAN_B;         // scan blocks (~13)

    // Carve (~56.2MB). H is scanned in place (becomes O).
    size_t off = 0;
    auto carve = [&](size_t bytes) -> void* {
        void* r = (void*)((char*)d_ws + off);
        off += (bytes + 255) & ~(size_t)255;
        return r;
    };
    float*        dinv    = (float*)carve((size_t)N * 4);
    float*        dxw1    = (float*)carve((size_t)N * 4 * 4);
    float*        dxw2    = (float*)carve((size_t)N * 4 * 4);
    float*        dxw3    = (float*)carve((size_t)N * 2 * 4);
    unsigned int* indptr  = (unsigned int*)carve(((size_t)N + 1) * 4);
    uint32_t*     bsum    = (uint32_t*)carve(260 * 4);
    uint32_t*     H       = (uint32_t*)carve(((size_t)M + 1) * 4);  // -> O in place
    uint32_t*     bpack   = (uint32_t*)carve((size_t)E * 4);
    int*          csr_row = (int*)carve((size_t)E * 4);
    bool use_bucket = (off <= ws_size) && (NB <= 1024) && (N < (1 << 23));

    if (use_bucket) {
        size_t sort_lds = (size_t)SORT_CAP * 4;  // 140KB dynamic (+4KB static)
        hipFuncSetAttribute((const void*)p_sort,
                            hipFuncAttributeMaxDynamicSharedMemorySize,
                            (int)sort_lds);
        p_hist<<<PART_B, PART_T, 0, stream>>>(col, H, NB, E, PBE);
        k_scan1<<<nblkS, SCAN_T, 0, stream>>>(H, H, bsum, M);         // in-place
        k_scan2<<<1, 32, 0, stream>>>(bsum, nblkS);
        k_scan3<<<nblkM, TPB, 0, stream>>>(H, bsum, H, M, E);         // in-place
        p_part<<<PART_B, PART_T, 0, stream>>>(row, col, H, bpack, NB, E, PBE);
        p_sort<<<NB, PART_T, sort_lds, stream>>>(bpack, H, csr_row, indptr,
                                                 dinv, NB, N, E);
        k_xw1d<<<nblkX, TPB, 0, stream>>>(x, W1, dinv, dxw1, N);
        k_gather44<<<nblkG, TPB, 0, stream>>>(indptr, csr_row, dinv, dxw1, b1, W2, dxw2, N);
        k_gather42<<<nblkG, TPB, 0, stream>>>(indptr, csr_row, dinv, dxw2, b2, W3, dxw3, N);
        k_gather2out<<<nblkG, TPB, 0, stream>>>(indptr, csr_row, dinv, dxw3, b3, Wc, bc,
                                                out, y3out, N);
    } else {
        // R3 verified atomic-push fallback: recarve from base (~6MB).
        size_t foff = 0;
        auto fcarve = [&](size_t bytes) -> void* {
            void* r = (void*)((char*)d_ws + foff);
            foff += (bytes + 255) & ~(size_t)255;
            return r;
        };
        unsigned int* deg   = (unsigned int*)fcarve((size_t)N * 4);
        float*        fdinv = (float*)fcarve((size_t)N * 4);
        float*        xw    = (float*)fcarve((size_t)N * 4 * 4);
        float*        agg   = (float*)fcarve((size_t)N * 4 * 4);
        float*        xw3   = (float*)fcarve((size_t)N * 2 * 4);
        float*        agg3  = (float*)fcarve((size_t)N * 2 * 4);
        k_zero_deg<<<nblkN, TPB, 0, stream>>>(deg, N);
        k_deg<<<nblkE, TPB, 0, stream>>>(col, deg, E);
        k_dinv<<<nblkN, TPB, 0, stream>>>(deg, fdinv, N);
        k_xw1<<<nblkW, TPB, 0, stream>>>(x, W1, fdinv, xw, agg, N);
        k_prop4<<<nblkE, TPB, 0, stream>>>(row, col, fdinv, xw, agg, E);
        k_node2<<<nblkN, TPB, 0, stream>>>(b1, W2, fdinv, xw, agg, N);
        k_prop4<<<nblkE, TPB, 0, stream>>>(row, col, fdinv, xw, agg, E);
        k_node3<<<nblkN, TPB, 0, stream>>>(b2, W3, fdinv, agg, xw3, agg3, N);
        k_prop2<<<nblkE, TPB, 0, stream>>>(row, col, fdinv, xw3, agg3, E);
        k_out<<<nblkN, TPB, 0, stream>>>(b3, Wc, bc, agg3, out, y3out, N);
    }
}